// Round 6
// baseline (324.254 us; speedup 1.0000x reference)
//
#include <hip/hip_runtime.h>

#define HH 128
#define WW 128
#define CC 64
#define OCC 128
#define NB 4
#define HW (HH * WW)
#define ROWB 296   // xs row stride (bf16 elems)

typedef short bf16x8 __attribute__((ext_vector_type(8)));
typedef float f32x4 __attribute__((ext_vector_type(4)));

// ws layout (bytes):
//   off : float[4][18][128][128]   at 0        (4718592 B)
//   wAf : ushort[8][2][9][64][8]   at 4718592  (147456 B)   A-frags for w_conv (bf16)
//   wpt : float[64][18][9]         at 4866048  (41472 B)    fp32 transposed w_p
#define WAF_OFS_B 4718592
#define WPT_OFS_B 4866048

__device__ inline unsigned short tobf16(float v) {
    unsigned int u = __float_as_uint(v);
    u += 0x7fffu + ((u >> 16) & 1u);
    return (unsigned short)(u >> 16);
}
__device__ inline float frombf16(unsigned short s) {
    return __uint_as_float(((unsigned int)s) << 16);
}
__device__ inline unsigned int bf16pair(float a, float b) {
    return (unsigned int)tobf16(a) | ((unsigned int)tobf16(b) << 16);
}

// wAf fragment order: flat = (((t*2+h)*9 + s)*64 + l)*8 + e
//   o = t*16 + (l&15);  k-octet = l>>4; channel c = h*32 + (l>>4)*8 + e
__global__ void prep_weights(const float* __restrict__ w_p,
                             const float* __restrict__ w_conv,
                             unsigned short* __restrict__ wAf,
                             float* __restrict__ wpt) {
    int idx = blockIdx.x * 256 + threadIdx.x;
    if (idx < 73728) {
        int e = idx & 7, l = (idx >> 3) & 63;
        int q = idx >> 9;
        int s = q % 9, q2 = q / 9;
        int h = q2 & 1, t = q2 >> 1;
        int o = t * 16 + (l & 15);
        int c = h * 32 + ((l >> 4) << 3) + e;
        wAf[idx] = tobf16(w_conv[(o * 64 + c) * 9 + s]);
    }
    int idx2 = idx - 73728;
    if (idx2 >= 0 && idx2 < 10368) {
        int c = idx2 / 162;
        int r = idx2 % 162;
        int n = r / 9, tap = r % 9;
        wpt[idx2] = w_p[(n * CC + c) * 9 + tap];
    }
}

// fp32 offset conv (bit-identical to R2's passing version).
__global__ __launch_bounds__(256) void offset_conv(
        const float* __restrict__ feat,
        const float* __restrict__ b_p,
        const float* __restrict__ wpt,   // [64][18][9]
        float* __restrict__ off) {       // [4][18][128][128]
    __shared__ float red[4][18][64];

    int bid = blockIdx.x;
    int jh = bid & 1;
    int i  = (bid >> 1) & 127;
    int b  = bid >> 8;
    int tid = threadIdx.x;
    int lane = tid & 63;
    int w = tid >> 6;
    int j = jh * 64 + lane;
    int c0 = w * 16;

    float acc[18];
#pragma unroll
    for (int n = 0; n < 18; ++n) acc[n] = 0.f;

    const float* fb = feat + b * CC * HW;
    const bool im1 = (i > 0), ip1 = (i < HH - 1);
    const bool jm1 = (j > 0), jp1 = (j < WW - 1);

    for (int cc = 0; cc < 16; ++cc) {
        int c = c0 + cc;
        const float* fc = fb + c * HW + i * WW + j;
        float f0 = (im1 && jm1) ? fc[-WW - 1] : 0.f;
        float f1 = im1          ? fc[-WW]     : 0.f;
        float f2 = (im1 && jp1) ? fc[-WW + 1] : 0.f;
        float f3 = jm1          ? fc[-1]      : 0.f;
        float f4 =                fc[0];
        float f5 = jp1          ? fc[1]       : 0.f;
        float f6 = (ip1 && jm1) ? fc[WW - 1]  : 0.f;
        float f7 = ip1          ? fc[WW]      : 0.f;
        float f8 = (ip1 && jp1) ? fc[WW + 1]  : 0.f;
        const float* wr = wpt + c * 162;
#pragma unroll
        for (int n = 0; n < 18; ++n) {
            acc[n] = fmaf(f0, wr[n * 9 + 0], acc[n]);
            acc[n] = fmaf(f1, wr[n * 9 + 1], acc[n]);
            acc[n] = fmaf(f2, wr[n * 9 + 2], acc[n]);
            acc[n] = fmaf(f3, wr[n * 9 + 3], acc[n]);
            acc[n] = fmaf(f4, wr[n * 9 + 4], acc[n]);
            acc[n] = fmaf(f5, wr[n * 9 + 5], acc[n]);
            acc[n] = fmaf(f6, wr[n * 9 + 6], acc[n]);
            acc[n] = fmaf(f7, wr[n * 9 + 7], acc[n]);
            acc[n] = fmaf(f8, wr[n * 9 + 8], acc[n]);
        }
    }
#pragma unroll
    for (int n = 0; n < 18; ++n) red[w][n][lane] = acc[n];
    __syncthreads();

    for (int it = tid; it < 18 * 64; it += 256) {
        int n = it >> 6, jj = it & 63;
        float v = b_p[n] + red[0][n][jj] + red[1][n][jj]
                         + red[2][n][jj] + red[3][n][jj];
        off[(b * 18 + n) * HW + i * WW + jh * 64 + jj] = v;
    }
}

// PROBE: identical staging (bf16 xs, bf16 wAf fragments), but the
// contraction is explicit VALU math pairing w and x by index — correct
// independent of any MFMA layout assumption. Epilogue mapping identical
// to the MFMA version's (acc[tl][nt][r] -> same o,pos).
__global__ __launch_bounds__(256) void dcn_main(
        const float* __restrict__ feat,
        const float* __restrict__ b_conv,
        const float* __restrict__ off,
        const unsigned short* __restrict__ wAf,
        float* __restrict__ out) {
    __shared__ __align__(16) unsigned short xs[64 * ROWB];

    int bid = blockIdx.x;
    int jh = bid & 1, i = (bid >> 1) & 127, b = bid >> 8;
    int j0 = jh * 64;
    int tid = threadIdx.x, lane = tid & 63;
    int wu = __builtin_amdgcn_readfirstlane(tid >> 6);

    float acc[2][4][4];   // [tl][nt][r]
#pragma unroll
    for (int tl = 0; tl < 2; ++tl)
#pragma unroll
        for (int nt = 0; nt < 4; ++nt)
#pragma unroll
            for (int r = 0; r < 4; ++r) acc[tl][nt][r] = 0.f;

    int m16 = (lane >> 4) << 2;   // D-row base within 16 (per m89 C/D map)

    for (int h = 0; h < 2; ++h) {
        // ---- phase 1: bilinear gather (identical to R5) ----
        for (int item = tid; item < 576; item += 256) {
            int n = item >> 6, pos = item & 63;
            int j = j0 + pos, sp = i * WW + j;
            float offx = off[(b * 18 + n) * HW + sp];
            float offy = off[(b * 18 + 9 + n) * HW + sp];
            float px = (float)(i + n / 3) + offx;
            float py = (float)(j + n % 3) + offy;
            float qxf = floorf(px), qyf = floorf(py);
            int x0 = min(max((int)qxf, 0), HH - 1);
            int y0 = min(max((int)qyf, 0), WW - 1);
            int x1 = min(max((int)qxf + 1, 0), HH - 1);
            int y1 = min(max((int)qyf + 1, 0), WW - 1);
            float pxc = fminf(fmaxf(px, 0.f), (float)(HH - 1));
            float pyc = fminf(fmaxf(py, 0.f), (float)(WW - 1));
            float gx0 = 1.f + ((float)x0 - pxc);
            float gx1 = 1.f - ((float)x1 - pxc);
            float gy0 = 1.f + ((float)y0 - pyc);
            float gy1 = 1.f - ((float)y1 - pyc);
            float glt = gx0 * gy0, grb = gx1 * gy1;
            float glb = gx0 * gy1, grt = gx1 * gy0;
            int o00 = x0 * WW + y0, o11 = x1 * WW + y1;
            int o01 = x0 * WW + y1, o10 = x1 * WW + y0;
            const float* fc = feat + (b * 64 + h * 32) * HW;
            unsigned int pk[16];
#pragma unroll
            for (int p = 0; p < 16; ++p) {
                float v0 = glt * fc[o00] + grb * fc[o11] + glb * fc[o01] + grt * fc[o10];
                fc += HW;
                float v1 = glt * fc[o00] + grb * fc[o11] + glb * fc[o01] + grt * fc[o10];
                fc += HW;
                pk[p] = bf16pair(v0, v1);
            }
            uint4* dst = (uint4*)&xs[pos * ROWB + n * 32];
#pragma unroll
            for (int q = 0; q < 4; ++q)
                dst[q] = make_uint4(pk[4 * q], pk[4 * q + 1], pk[4 * q + 2], pk[4 * q + 3]);
        }
        __syncthreads();

        // ---- phase 2 (probe): explicit contraction from same buffers ----
        for (int s = 0; s < 9; ++s) {
#pragma unroll
            for (int kg = 0; kg < 4; ++kg) {
                bf16x8 xv[4];
#pragma unroll
                for (int nt = 0; nt < 4; ++nt)
                    xv[nt] = *(const bf16x8*)
                        &xs[(nt * 16 + (lane & 15)) * ROWB + s * 32 + kg * 8];
#pragma unroll
                for (int tl = 0; tl < 2; ++tl) {
#pragma unroll
                    for (int r = 0; r < 4; ++r) {
                        int lp = kg * 16 + m16 + r;   // fragment-lane holding A[m][kg-octet]
                        bf16x8 wv = *(const bf16x8*)
                            &wAf[((((wu * 2 + tl) * 2 + h) * 9 + s) * 64 + lp) * 8];
#pragma unroll
                        for (int e = 0; e < 8; ++e) {
                            float wf = frombf16((unsigned short)wv[e]);
#pragma unroll
                            for (int nt = 0; nt < 4; ++nt)
                                acc[tl][nt][r] = fmaf(
                                    wf, frombf16((unsigned short)xv[nt][e]),
                                    acc[tl][nt][r]);
                        }
                    }
                }
            }
        }
        __syncthreads();
    }

    // ---- epilogue (identical mapping to the MFMA version) ----
#pragma unroll
    for (int tl = 0; tl < 2; ++tl)
#pragma unroll
        for (int nt = 0; nt < 4; ++nt)
#pragma unroll
            for (int r = 0; r < 4; ++r) {
                int o = (wu * 2 + tl) * 16 + m16 + r;
                int pos = nt * 16 + (lane & 15);
                out[((b * OCC + o) * HH + i) * WW + j0 + pos] =
                    acc[tl][nt][r] + b_conv[o];
            }
}

extern "C" void kernel_launch(void* const* d_in, const int* in_sizes, int n_in,
                              void* d_out, int out_size, void* d_ws, size_t ws_size,
                              hipStream_t stream) {
    const float* feat   = (const float*)d_in[0];
    const float* w_p    = (const float*)d_in[1];
    const float* b_p    = (const float*)d_in[2];
    const float* w_conv = (const float*)d_in[3];
    const float* b_conv = (const float*)d_in[4];
    float* out = (float*)d_out;
    char* ws   = (char*)d_ws;

    float* off = (float*)ws;
    unsigned short* wAf = (unsigned short*)(ws + WAF_OFS_B);
    float* wpt          = (float*)(ws + WPT_OFS_B);

    hipLaunchKernelGGL(prep_weights, dim3(329), dim3(256), 0, stream,
                       w_p, w_conv, wAf, wpt);
    hipLaunchKernelGGL(offset_conv, dim3(NB * 128 * 2), dim3(256), 0, stream,
                       feat, b_p, wpt, off);
    hipLaunchKernelGGL(dcn_main, dim3(NB * 128 * 2), dim3(256), 0, stream,
                       feat, b_conv, off, wAf, out);
}